// Round 8
// baseline (185.760 us; speedup 1.0000x reference)
//
#include <hip/hip_runtime.h>
#include <math.h>

// Problem constants (match reference)
#define B_   16
#define T_   1024
#define F_   512
#define G_   2
#define V_   320
#define D_   128
#define N_   (B_ * T_)      // 16384 tokens
#define GV   (G_ * V_)      // 640
#define EPS_ 1e-7f

// Fused-GEMM: barrier-free, LDS-free phase 1. Dual-limb f16 MFMA:
//   logits = xh*wh + 2^-11*(xl*wh + xh*wl)
// W fragments stream L2->reg (wpk packed layout); x fragments are loaded
// per-lane DIRECTLY from global (each lane's A-fragment is contiguous 32 B:
// x[wvm*32+lo][c*16+hi*8 .. +8] -- identical values to R7's LDS staging map).
#define ROWS    64
#define THREADS 512          // 8 waves: 2(M=wvm) x 4(N=wvn) wave grid
#define NBLK    (N_ / ROWS)  // 256 blocks -> 1 block/CU
#define NC      32           // K=16 per chunk

typedef _Float16 half8 __attribute__((ext_vector_type(8)));
typedef float f32x16 __attribute__((ext_vector_type(16)));

// Workspace layout (float slots). counts PACKED u32 (2 x u16, count<=16).
#define CNTW      (T_ * G_ * (V_ / 2))      // 327680 u32 words
#define WS_COUNTS 0
#define WS_AVG    CNTW                      // NBLK*GV = 163840
#define WS_ENT    (WS_AVG + NBLK * GV)      // T_*G_   = 2048
#define WS_WPK    (WS_ENT + T_ * G_)        // packed w limbs: 655360 halves
#define WS_AVGRED (WS_WPK + (GV * F_ * 2 / 2))

// ---- w -> packed fragment-order f16 limbs (+ fused counts zeroing) ----
// wpk half8 index: ((c*2 + limb)*20 + m)*64 + ln
//   contents: w[m*32 + (ln&31)][c*16 + (ln>>5)*8 + j] limb-converted.
__global__ __launch_bounds__(640) void k_conv_w(
    const float* __restrict__ w, _Float16* __restrict__ wpk,
    unsigned* __restrict__ counts)
{
  const int cl = blockIdx.x;     // 0..63 = c*2 + limb
  const int c = cl >> 1, limb = cl & 1;
#pragma unroll
  for (int z = 0; z < 8; ++z)    // zero counts: 64*640*8 = 327680 words
    counts[(size_t)z * 40960 + blockIdx.x * 640 + threadIdx.x] = 0u;
#pragma unroll
  for (int it = 0; it < 2; ++it) {
    const int t2 = threadIdx.x + it * 640;   // 0..1279
    const int m = t2 >> 6, ln = t2 & 63;
    const int row = m * 32 + (ln & 31);
    const int k0 = c * 16 + (ln >> 5) * 8;
    const float4 v0 = *(const float4*)(w + (size_t)row * F_ + k0);
    const float4 v1 = *(const float4*)(w + (size_t)row * F_ + k0 + 4);
    half8 h;
#pragma unroll
    for (int k = 0; k < 8; ++k) {
      const float vk = (k < 4) ? ((const float*)&v0)[k] : ((const float*)&v1)[k - 4];
      const _Float16 hk = (_Float16)vk;
      h[k] = limb ? (_Float16)((vk - (float)hk) * 2048.0f) : hk;
    }
    ((half8*)wpk)[((size_t)cl * 20 + m) * 64 + ln] = h;
  }
}

// Fused: barrier-free dual-limb MFMA GEMM + softmax stats + gather.
__global__ __launch_bounds__(THREADS, 1) void k_fused(
    const float* __restrict__ x, const _Float16* __restrict__ wpk,
    const float* __restrict__ bias, const float* __restrict__ cb,
    const float* __restrict__ gum, float* __restrict__ out,
    unsigned* __restrict__ counts, float* __restrict__ avg_part)
{
  __shared__ float SB2[16 * GV];      // 40 KB: phase-2 LBUF only
  const int tid = threadIdx.x;
  const int wv  = tid >> 6;           // 0..7
  const int ln  = tid & 63;
  const int lo  = ln & 31, hi = ln >> 5;
  const int wvm = wv >> 2, wvn = wv & 3;
  const int blk = blockIdx.x;
  const int n0  = blk * ROWS;

  f32x16 ah_acc[5], al_acc[5];
#pragma unroll
  for (int t = 0; t < 5; ++t)
#pragma unroll
    for (int i = 0; i < 16; ++i) { ah_acc[t][i] = 0.0f; al_acc[t][i] = 0.0f; }

  // per-wave global fragment bases
  const half8* wbase = (const half8*)wpk + (size_t)(wvn * 5) * 64 + ln;
  const float* xrow  = x + (size_t)(n0 + wvm * 32 + lo) * F_ + hi * 8;

  // ---- prologue: chunk-0 fragments into registers ----
  half8 wch[5], wcl[5];
#pragma unroll
  for (int t = 0; t < 5; ++t) {
    wch[t] = wbase[(size_t)(0 * 20 + t) * 64];
    wcl[t] = wbase[(size_t)(1 * 20 + t) * 64];
  }
  float4 xc0 = *(const float4*)(xrow + 0);
  float4 xc1 = *(const float4*)(xrow + 4);

  // ---- main loop: no LDS, no barriers; 1-chunk register prefetch ----
  for (int cc = 0; cc < NC; ++cc) {
    const int c1 = (cc + 1 < NC) ? cc + 1 : cc;   // clamped (last reload dead)
    half8 wnh[5], wnl[5];
#pragma unroll
    for (int t = 0; t < 5; ++t) {
      wnh[t] = wbase[((size_t)(c1 * 2 + 0) * 20 + t) * 64];
      wnl[t] = wbase[((size_t)(c1 * 2 + 1) * 20 + t) * 64];
    }
    const float4 xn0 = *(const float4*)(xrow + c1 * 16);
    const float4 xn1 = *(const float4*)(xrow + c1 * 16 + 4);

    // convert current x to limbs (same numerics as R7 STAGE_A)
    half8 xh8, xl8;
#pragma unroll
    for (int k = 0; k < 8; ++k) {
      const float f = (k < 4) ? ((const float*)&xc0)[k] : ((const float*)&xc1)[k - 4];
      const _Float16 h = (_Float16)f;
      xh8[k] = h;
      xl8[k] = (_Float16)((f - (float)h) * 2048.0f);
    }
#pragma unroll
    for (int t = 0; t < 5; ++t) {
      ah_acc[t] = __builtin_amdgcn_mfma_f32_32x32x16_f16(xh8, wch[t], ah_acc[t], 0, 0, 0);
      al_acc[t] = __builtin_amdgcn_mfma_f32_32x32x16_f16(xl8, wch[t], al_acc[t], 0, 0, 0);
      al_acc[t] = __builtin_amdgcn_mfma_f32_32x32x16_f16(xh8, wcl[t], al_acc[t], 0, 0, 0);
    }
    // rotate prefetched fragments into current
#pragma unroll
    for (int t = 0; t < 5; ++t) { wch[t] = wnh[t]; wcl[t] = wnl[t]; }
    xc0 = xn0; xc1 = xn1;
  }

  // ---- phase 2 (verbatim R7): softmax / argmax / gather via 16-row slabs ----
  float bfrag[5];
#pragma unroll
  for (int t = 0; t < 5; ++t) bfrag[t] = bias[wvn * 160 + t * 32 + lo];

  float racc[G_][5];
#pragma unroll
  for (int g = 0; g < G_; ++g)
#pragma unroll
    for (int j = 0; j < 5; ++j) racc[g][j] = 0.f;

  float* LBUF = SB2;  // [16][640]

#pragma unroll
  for (int R = 0; R < 4; ++R) {
    // writers: waves with wvm==R>>1 dump regs 8*(R&1)..+7 (C/D layout:
    // col=lane&31, row=(reg&3)+8*(reg>>2)+4*hi) -> rows 16R..16R+15
    if (wvm == (R >> 1)) {
#pragma unroll
      for (int t = 0; t < 5; ++t) {
        const int col = wvn * 160 + t * 32 + lo;
#pragma unroll
        for (int rr = 0; rr < 8; ++rr) {
          const int reg  = ((R & 1) << 3) + rr;
          const int lrow = (rr & 3) + ((rr >> 2) << 3) + (hi << 2);
          LBUF[lrow * GV + col] =
              ah_acc[t][reg] + al_acc[t][reg] * (1.0f / 2048.0f) + bfrag[t];
        }
      }
    }
    __syncthreads();
#pragma unroll
    for (int rr2 = 0; rr2 < 2; ++rr2) {
      const int lrow = wv * 2 + rr2;
      const int n = n0 + R * 16 + lrow;
#pragma unroll
      for (int g = 0; g < G_; ++g) {
        float L[5], GU[5];
#pragma unroll
        for (int j = 0; j < 5; ++j) {
          L[j]  = LBUF[lrow * GV + g * V_ + 64 * j + ln];
          GU[j] = gum[(size_t)n * GV + g * V_ + 64 * j + ln];
        }
        // local max/argmax (cols ascend with j -> first-occurrence tie-break)
        float m1 = L[0];         int a1 = ln;
        float m2 = L[0] + GU[0]; int a2 = ln;
#pragma unroll
        for (int j = 1; j < 5; ++j) {
          const int cix = 64 * j + ln;
          if (L[j] > m1) { m1 = L[j]; a1 = cix; }
          const float t2 = L[j] + GU[j];
          if (t2 > m2) { m2 = t2; a2 = cix; }
        }
        // wave reduce (prefer smaller index on exact ties)
        for (int off = 32; off; off >>= 1) {
          float om = __shfl_down(m1, off); int oa = __shfl_down(a1, off);
          if (om > m1 || (om == m1 && oa < a1)) { m1 = om; a1 = oa; }
          float om2 = __shfl_down(m2, off); int oa2 = __shfl_down(a2, off);
          if (om2 > m2 || (om2 == m2 && oa2 < a2)) { m2 = om2; a2 = oa2; }
        }
        m1 = __shfl(m1, 0); a1 = __shfl(a1, 0); a2 = __shfl(a2, 0);

        // softmax (no tau) for avg_probs
        float e[5], s = 0.f;
#pragma unroll
        for (int j = 0; j < 5; ++j) { e[j] = expf(L[j] - m1); s += e[j]; }
        for (int off = 32; off; off >>= 1) s += __shfl_down(s, off);
        s = __shfl(s, 0);
        const float inv = 1.0f / s;
#pragma unroll
        for (int j = 0; j < 5; ++j) racc[g][j] += e[j] * inv;

        if (ln == 0) {
          const int t = n & (T_ - 1);
          // packed 16-bit histogram bump (count <= 16, no carry possible)
          atomicAdd(&counts[(t * G_ + g) * (V_ / 2) + (a1 >> 1)],
                    1u << ((a1 & 1) * 16));
        }
        // quantized[n, g*D : (g+1)*D] = codebook[g, a2, :]
        const float2* cbr = (const float2*)(cb + (size_t)(g * V_ + a2) * D_);
        float2* op = (float2*)(out + (size_t)n * (G_ * D_) + g * D_);
        op[ln] = cbr[ln];
      }
    }
    __syncthreads();
  }

  // ---- block-level avg_probs partial: reduce 8 wave-private copies ----
  float* la = SB2;  // [8][GV] = 20480 B
#pragma unroll
  for (int g = 0; g < G_; ++g)
#pragma unroll
    for (int j = 0; j < 5; ++j)
      la[wv * GV + g * V_ + 64 * j + ln] = racc[g][j];
  __syncthreads();
  for (int cix = tid; cix < GV; cix += THREADS) {
    float s = 0.f;
#pragma unroll
    for (int v = 0; v < 8; ++v) s += la[v * GV + cix];
    avg_part[(size_t)blk * GV + cix] = s;
  }
}

// Merged post-pass (one launch): blocks 0..511 = per-(t,g) histogram entropy;
// blocks 512..671 = column reduce of avg_part -> avgred.
__global__ __launch_bounds__(256) void k_post(
    const unsigned* __restrict__ counts, float* __restrict__ ent,
    const float* __restrict__ avg_part, float* __restrict__ avgred)
{
  const int b = blockIdx.x;
  const int lane = threadIdx.x & 63;
  if (b < (T_ * G_) / 4) {
    const int item = b * 4 + (threadIdx.x >> 6);  // 0..2047
    const unsigned* c = counts + (size_t)item * (V_ / 2);
    float s = 0.f;
#pragma unroll
    for (int j = 0; j < 3; ++j) {
      const int wi = lane + 64 * j;
      if (wi < V_ / 2) {
        const unsigned wd = c[wi];
        const float h0 = (float)(wd & 0xffffu) * (1.0f / B_);
        const float h1 = (float)(wd >> 16) * (1.0f / B_);
        s += h0 * logf(h0 + EPS_) + h1 * logf(h1 + EPS_);
      }
    }
    for (int off = 32; off; off >>= 1) s += __shfl_down(s, off);
    if (lane == 0) ent[item] = expf(-s);
  } else {
    const int cix = (b - (T_ * G_) / 4) * 4 + (threadIdx.x >> 6);  // 0..639
    float s = 0.f;
    for (int bb = lane; bb < NBLK; bb += 64) s += avg_part[(size_t)bb * GV + cix];
    for (int off = 32; off; off >>= 1) s += __shfl_down(s, off);
    if (lane == 0) avgred[cix] = s;
  }
}

// Finalize both scalars. Single block of 640 threads.
__global__ __launch_bounds__(GV) void k_final(
    const float* __restrict__ avgred, const float* __restrict__ ent,
    float* __restrict__ out2)
{
  __shared__ float sh[GV];   // p*log(p+eps) per column
  __shared__ float shc[GV];  // code-entropy partials
  const int tid = threadIdx.x;

  const float p = avgred[tid] * (1.0f / N_);
  sh[tid] = p * logf(p + EPS_);

  float cs = 0.f;
  for (int i = tid; i < T_ * G_; i += GV) cs += ent[i];
  shc[tid] = cs;
  __syncthreads();

  if (tid < 64) {
    float s0 = 0.f, s1 = 0.f, sc = 0.f;
    for (int j = tid; j < V_; j += 64) { s0 += sh[j]; s1 += sh[V_ + j]; }
    for (int j = tid; j < GV; j += 64) sc += shc[j];
    for (int off = 32; off; off >>= 1) {
      s0 += __shfl_down(s0, off);
      s1 += __shfl_down(s1, off);
      sc += __shfl_down(sc, off);
    }
    if (tid == 0) {
      out2[0] = sc;                          // code_perplexity
      out2[1] = expf(-s0) + expf(-s1);       // prob_perplexity
    }
  }
}

extern "C" void kernel_launch(void* const* d_in, const int* in_sizes, int n_in,
                              void* d_out, int out_size, void* d_ws, size_t ws_size,
                              hipStream_t stream) {
  const float* x   = (const float*)d_in[0];  // (B,T,F)
  const float* w   = (const float*)d_in[1];  // (G*V, F)
  const float* b   = (const float*)d_in[2];  // (G*V,)
  const float* cb  = (const float*)d_in[3];  // (1, G*V, D)
  const float* gum = (const float*)d_in[4];  // (B*T, G, V)
  float* out = (float*)d_out;                // quantized (N*G*D) ++ [code_ppl, prob_ppl]
  float* ws  = (float*)d_ws;

  unsigned* counts = (unsigned*)(ws + WS_COUNTS);
  float* avgp   = ws + WS_AVG;
  float* ent    = ws + WS_ENT;
  _Float16* wpk = (_Float16*)(ws + WS_WPK);
  float* avgred = ws + WS_AVGRED;

  k_conv_w<<<64, 640, 0, stream>>>(w, wpk, counts);
  k_fused<<<NBLK, THREADS, 0, stream>>>(x, wpk, b, cb, gum, out, counts, avgp);
  k_post<<<(T_ * G_) / 4 + GV / 4, 256, 0, stream>>>(counts, ent, avgp, avgred);
  k_final<<<1, GV, 0, stream>>>(avgred, ent, out + (size_t)N_ * G_ * D_);
}

// Round 9
// 176.741 us; speedup vs baseline: 1.0510x; 1.0510x over previous
//
#include <hip/hip_runtime.h>
#include <math.h>

// Problem constants (match reference)
#define B_   16
#define T_   1024
#define F_   512
#define G_   2
#define V_   320
#define D_   128
#define N_   (B_ * T_)      // 16384 tokens
#define GV   (G_ * V_)      // 640
#define EPS_ 1e-7f

// Fused-GEMM: t-outer dual-limb f16 MFMA, barrier-free main loop.
//   logits = xh*wh + 2^-11*(xl*wh + xh*wl)
// x limbs converted ONCE into LDS (fragment order); W streams L2->reg with
// distance-2 two-set pipeline; only one al tile live (folded per t-sweep).
#define ROWS    64
#define THREADS 512          // 8 waves: 2(M=wvm) x 4(N=wvn) wave grid
#define NBLK    (N_ / ROWS)  // 256 blocks -> 1 block/CU
#define NC      32           // K=16 per chunk

typedef _Float16 half8 __attribute__((ext_vector_type(8)));
typedef _Float16 half4 __attribute__((ext_vector_type(4)));
typedef float f32x16 __attribute__((ext_vector_type(16)));

// Workspace layout (float slots). counts PACKED u32 (2 x u16, count<=16).
#define CNTW      (T_ * G_ * (V_ / 2))      // 327680 u32 words
#define WS_COUNTS 0
#define WS_AVG    CNTW                      // NBLK*GV = 163840
#define WS_ENT    (WS_AVG + NBLK * GV)      // T_*G_   = 2048
#define WS_WPK    (WS_ENT + T_ * G_)        // packed w limbs: 655360 halves
#define WS_AVGRED (WS_WPK + (GV * F_ * 2 / 2))

// ---- w -> packed fragment-order f16 limbs (+ fused counts zeroing) ----
// wpk half8 index: ((c*2 + limb)*20 + m)*64 + ln
//   contents: w[m*32 + (ln&31)][c*16 + (ln>>5)*8 + j] limb-converted.
__global__ __launch_bounds__(640) void k_conv_w(
    const float* __restrict__ w, _Float16* __restrict__ wpk,
    unsigned* __restrict__ counts)
{
  const int cl = blockIdx.x;     // 0..63 = c*2 + limb
  const int c = cl >> 1, limb = cl & 1;
#pragma unroll
  for (int z = 0; z < 8; ++z)    // zero counts: 64*640*8 = 327680 words
    counts[(size_t)z * 40960 + blockIdx.x * 640 + threadIdx.x] = 0u;
#pragma unroll
  for (int it = 0; it < 2; ++it) {
    const int t2 = threadIdx.x + it * 640;   // 0..1279
    const int m = t2 >> 6, ln = t2 & 63;
    const int row = m * 32 + (ln & 31);
    const int k0 = c * 16 + (ln >> 5) * 8;
    const float4 v0 = *(const float4*)(w + (size_t)row * F_ + k0);
    const float4 v1 = *(const float4*)(w + (size_t)row * F_ + k0 + 4);
    half8 h;
#pragma unroll
    for (int k = 0; k < 8; ++k) {
      const float vk = (k < 4) ? ((const float*)&v0)[k] : ((const float*)&v1)[k - 4];
      const _Float16 hk = (_Float16)vk;
      h[k] = limb ? (_Float16)((vk - (float)hk) * 2048.0f) : hk;
    }
    ((half8*)wpk)[((size_t)cl * 20 + m) * 64 + ln] = h;
  }
}

// Fused: t-outer barrier-free dual-limb MFMA GEMM + softmax stats + gather.
__global__ __launch_bounds__(THREADS, 1) void k_fused(
    const float* __restrict__ x, const _Float16* __restrict__ wpk,
    const float* __restrict__ bias, const float* __restrict__ cb,
    const float* __restrict__ gum, float* __restrict__ out,
    unsigned* __restrict__ counts, float* __restrict__ avg_part)
{
  // x-limb store: elem (row r, k, limb L) at
  //   L*65536 + (k>>4)*2048 + (r>>5)*1024 + ((r&31) + 32*((k>>3)&1))*16 + (k&7)*2
  // -> fragment (wvm, chunk c, limb L) for lane ln is the contiguous 16 B at
  //   L*65536 + c*2048 + wvm*1024 + ln*16   (identical values to R8's frags).
  // Phase 2 reuses this region as LBUF[16][640] (40 KB) after a barrier.
  __shared__ __align__(16) unsigned char SB[131072];
  const int tid = threadIdx.x;
  const int wv  = tid >> 6;           // 0..7
  const int ln  = tid & 63;
  const int lo  = ln & 31, hi = ln >> 5;
  const int wvm = wv >> 2, wvn = wv & 3;
  const int blk = blockIdx.x;
  const int n0  = blk * ROWS;

  // ---- init: x -> LDS f16 limb fragments (once; the only phase-1 barrier) ----
  {
    const int row = tid >> 3, kq = tid & 7;
    const float* xr = x + (size_t)(n0 + row) * F_;
    const int rbase = ((row >> 5) * 1024) + ((row & 31) * 16);
#pragma unroll
    for (int it = 0; it < 16; ++it) {
      const int k0 = it * 32 + kq * 4;
      const float4 v = *(const float4*)(xr + k0);
      half4 hh, hl;
#pragma unroll
      for (int k = 0; k < 4; ++k) {
        const float f = ((const float*)&v)[k];
        const _Float16 h = (_Float16)f;
        hh[k] = h;
        hl[k] = (_Float16)((f - (float)h) * 2048.0f);
      }
      const int ad = (k0 >> 4) * 2048 + rbase + ((k0 >> 3) & 1) * 512 + (k0 & 7) * 2;
      *(half4*)(SB + ad) = hh;
      *(half4*)(SB + 65536 + ad) = hl;
    }
  }
  __syncthreads();

  f32x16 ah[5];
#pragma unroll
  for (int t = 0; t < 5; ++t)
#pragma unroll
    for (int i = 0; i < 16; ++i) ah[t][i] = 0.0f;

  const half8* wp8 = (const half8*)wpk;
  const int xoff = wvm * 1024 + ln * 16;

  // ---- main loop: t-outer, zero barriers, 2-set distance-2 W pipeline ----
#pragma unroll
  for (int t = 0; t < 5; ++t) {
    const int g0 = wvn * 5 + t;
    f32x16 al;
#pragma unroll
    for (int i = 0; i < 16; ++i) al[i] = 0.0f;

    half8 wAh = wp8[(size_t)(0 * 40 + g0) * 64 + ln];
    half8 wAl = wp8[(size_t)(0 * 40 + 20 + g0) * 64 + ln];
    half8 wBh = wp8[(size_t)(1 * 40 + g0) * 64 + ln];
    half8 wBl = wp8[(size_t)(1 * 40 + 20 + g0) * 64 + ln];
    half8 xAh = *(const half8*)(SB + 0 * 2048 + xoff);
    half8 xAl = *(const half8*)(SB + 65536 + 0 * 2048 + xoff);

    for (int c = 0; c < NC; c += 2) {
      // x fragments for sub-iter B (c+1 <= 31 always)
      half8 xBh = *(const half8*)(SB + (c + 1) * 2048 + xoff);
      half8 xBl = *(const half8*)(SB + 65536 + (c + 1) * 2048 + xoff);
      __builtin_amdgcn_s_setprio(1);
      ah[t] = __builtin_amdgcn_mfma_f32_32x32x16_f16(xAh, wAh, ah[t], 0, 0, 0);
      al    = __builtin_amdgcn_mfma_f32_32x32x16_f16(xAl, wAh, al,    0, 0, 0);
      al    = __builtin_amdgcn_mfma_f32_32x32x16_f16(xAh, wAl, al,    0, 0, 0);
      __builtin_amdgcn_s_setprio(0);
      if (c + 2 < NC) {   // refill set A (distance 2)
        wAh = wp8[(size_t)((c + 2) * 40 + g0) * 64 + ln];
        wAl = wp8[(size_t)((c + 2) * 40 + 20 + g0) * 64 + ln];
        xAh = *(const half8*)(SB + (c + 2) * 2048 + xoff);
        xAl = *(const half8*)(SB + 65536 + (c + 2) * 2048 + xoff);
      }
      __builtin_amdgcn_s_setprio(1);
      ah[t] = __builtin_amdgcn_mfma_f32_32x32x16_f16(xBh, wBh, ah[t], 0, 0, 0);
      al    = __builtin_amdgcn_mfma_f32_32x32x16_f16(xBl, wBh, al,    0, 0, 0);
      al    = __builtin_amdgcn_mfma_f32_32x32x16_f16(xBh, wBl, al,    0, 0, 0);
      __builtin_amdgcn_s_setprio(0);
      if (c + 3 < NC) {   // refill set B (distance 2)
        wBh = wp8[(size_t)((c + 3) * 40 + g0) * 64 + ln];
        wBl = wp8[(size_t)((c + 3) * 40 + 20 + g0) * 64 + ln];
      }
    }
    // fold low-limb partial (full-K accumulation, same numerics as R8)
#pragma unroll
    for (int i = 0; i < 16; ++i) ah[t][i] += al[i] * (1.0f / 2048.0f);
  }
  __syncthreads();  // x-limb region dead; SB becomes LBUF below

  // ---- phase 2 (verbatim R8, al pre-folded): softmax / argmax / gather ----
  float bfrag[5];
#pragma unroll
  for (int t = 0; t < 5; ++t) bfrag[t] = bias[wvn * 160 + t * 32 + lo];

  float racc[G_][5];
#pragma unroll
  for (int g = 0; g < G_; ++g)
#pragma unroll
    for (int j = 0; j < 5; ++j) racc[g][j] = 0.f;

  float* LBUF = (float*)SB;  // [16][640]

#pragma unroll
  for (int R = 0; R < 4; ++R) {
    // writers: waves with wvm==R>>1 dump regs 8*(R&1)..+7 (C/D layout:
    // col=lane&31, row=(reg&3)+8*(reg>>2)+4*hi) -> rows 16R..16R+15
    if (wvm == (R >> 1)) {
#pragma unroll
      for (int t = 0; t < 5; ++t) {
        const int col = wvn * 160 + t * 32 + lo;
#pragma unroll
        for (int rr = 0; rr < 8; ++rr) {
          const int reg  = ((R & 1) << 3) + rr;
          const int lrow = (rr & 3) + ((rr >> 2) << 3) + (hi << 2);
          LBUF[lrow * GV + col] = ah[t][reg] + bfrag[t];
        }
      }
    }
    __syncthreads();
#pragma unroll
    for (int rr2 = 0; rr2 < 2; ++rr2) {
      const int lrow = wv * 2 + rr2;
      const int n = n0 + R * 16 + lrow;
#pragma unroll
      for (int g = 0; g < G_; ++g) {
        float L[5], GU[5];
#pragma unroll
        for (int j = 0; j < 5; ++j) {
          L[j]  = LBUF[lrow * GV + g * V_ + 64 * j + ln];
          GU[j] = gum[(size_t)n * GV + g * V_ + 64 * j + ln];
        }
        // local max/argmax (cols ascend with j -> first-occurrence tie-break)
        float m1 = L[0];         int a1 = ln;
        float m2 = L[0] + GU[0]; int a2 = ln;
#pragma unroll
        for (int j = 1; j < 5; ++j) {
          const int cix = 64 * j + ln;
          if (L[j] > m1) { m1 = L[j]; a1 = cix; }
          const float t2 = L[j] + GU[j];
          if (t2 > m2) { m2 = t2; a2 = cix; }
        }
        // wave reduce (prefer smaller index on exact ties)
        for (int off = 32; off; off >>= 1) {
          float om = __shfl_down(m1, off); int oa = __shfl_down(a1, off);
          if (om > m1 || (om == m1 && oa < a1)) { m1 = om; a1 = oa; }
          float om2 = __shfl_down(m2, off); int oa2 = __shfl_down(a2, off);
          if (om2 > m2 || (om2 == m2 && oa2 < a2)) { m2 = om2; a2 = oa2; }
        }
        m1 = __shfl(m1, 0); a1 = __shfl(a1, 0); a2 = __shfl(a2, 0);

        // softmax (no tau) for avg_probs
        float e[5], s = 0.f;
#pragma unroll
        for (int j = 0; j < 5; ++j) { e[j] = expf(L[j] - m1); s += e[j]; }
        for (int off = 32; off; off >>= 1) s += __shfl_down(s, off);
        s = __shfl(s, 0);
        const float inv = 1.0f / s;
#pragma unroll
        for (int j = 0; j < 5; ++j) racc[g][j] += e[j] * inv;

        if (ln == 0) {
          const int t = n & (T_ - 1);
          // packed 16-bit histogram bump (count <= 16, no carry possible)
          atomicAdd(&counts[(t * G_ + g) * (V_ / 2) + (a1 >> 1)],
                    1u << ((a1 & 1) * 16));
        }
        // quantized[n, g*D : (g+1)*D] = codebook[g, a2, :]
        const float2* cbr = (const float2*)(cb + (size_t)(g * V_ + a2) * D_);
        float2* op = (float2*)(out + (size_t)n * (G_ * D_) + g * D_);
        op[ln] = cbr[ln];
      }
    }
    __syncthreads();
  }

  // ---- block-level avg_probs partial: reduce 8 wave-private copies ----
  float* la = (float*)SB;  // [8][GV] = 20480 B
#pragma unroll
  for (int g = 0; g < G_; ++g)
#pragma unroll
    for (int j = 0; j < 5; ++j)
      la[wv * GV + g * V_ + 64 * j + ln] = racc[g][j];
  __syncthreads();
  for (int cix = tid; cix < GV; cix += THREADS) {
    float s = 0.f;
#pragma unroll
    for (int v = 0; v < 8; ++v) s += la[v * GV + cix];
    avg_part[(size_t)blk * GV + cix] = s;
  }
}

// Merged post-pass (one launch): blocks 0..511 = per-(t,g) histogram entropy;
// blocks 512..671 = column reduce of avg_part -> avgred.
__global__ __launch_bounds__(256) void k_post(
    const unsigned* __restrict__ counts, float* __restrict__ ent,
    const float* __restrict__ avg_part, float* __restrict__ avgred)
{
  const int b = blockIdx.x;
  const int lane = threadIdx.x & 63;
  if (b < (T_ * G_) / 4) {
    const int item = b * 4 + (threadIdx.x >> 6);  // 0..2047
    const unsigned* c = counts + (size_t)item * (V_ / 2);
    float s = 0.f;
#pragma unroll
    for (int j = 0; j < 3; ++j) {
      const int wi = lane + 64 * j;
      if (wi < V_ / 2) {
        const unsigned wd = c[wi];
        const float h0 = (float)(wd & 0xffffu) * (1.0f / B_);
        const float h1 = (float)(wd >> 16) * (1.0f / B_);
        s += h0 * logf(h0 + EPS_) + h1 * logf(h1 + EPS_);
      }
    }
    for (int off = 32; off; off >>= 1) s += __shfl_down(s, off);
    if (lane == 0) ent[item] = expf(-s);
  } else {
    const int cix = (b - (T_ * G_) / 4) * 4 + (threadIdx.x >> 6);  // 0..639
    float s = 0.f;
    for (int bb = lane; bb < NBLK; bb += 64) s += avg_part[(size_t)bb * GV + cix];
    for (int off = 32; off; off >>= 1) s += __shfl_down(s, off);
    if (lane == 0) avgred[cix] = s;
  }
}

// Finalize both scalars. Single block of 640 threads.
__global__ __launch_bounds__(GV) void k_final(
    const float* __restrict__ avgred, const float* __restrict__ ent,
    float* __restrict__ out2)
{
  __shared__ float sh[GV];   // p*log(p+eps) per column
  __shared__ float shc[GV];  // code-entropy partials
  const int tid = threadIdx.x;

  const float p = avgred[tid] * (1.0f / N_);
  sh[tid] = p * logf(p + EPS_);

  float cs = 0.f;
  for (int i = tid; i < T_ * G_; i += GV) cs += ent[i];
  shc[tid] = cs;
  __syncthreads();

  if (tid < 64) {
    float s0 = 0.f, s1 = 0.f, sc = 0.f;
    for (int j = tid; j < V_; j += 64) { s0 += sh[j]; s1 += sh[V_ + j]; }
    for (int j = tid; j < GV; j += 64) sc += shc[j];
    for (int off = 32; off; off >>= 1) {
      s0 += __shfl_down(s0, off);
      s1 += __shfl_down(s1, off);
      sc += __shfl_down(sc, off);
    }
    if (tid == 0) {
      out2[0] = sc;                          // code_perplexity
      out2[1] = expf(-s0) + expf(-s1);       // prob_perplexity
    }
  }
}

extern "C" void kernel_launch(void* const* d_in, const int* in_sizes, int n_in,
                              void* d_out, int out_size, void* d_ws, size_t ws_size,
                              hipStream_t stream) {
  const float* x   = (const float*)d_in[0];  // (B,T,F)
  const float* w   = (const float*)d_in[1];  // (G*V, F)
  const float* b   = (const float*)d_in[2];  // (G*V,)
  const float* cb  = (const float*)d_in[3];  // (1, G*V, D)
  const float* gum = (const float*)d_in[4];  // (B*T, G, V)
  float* out = (float*)d_out;                // quantized (N*G*D) ++ [code_ppl, prob_ppl]
  float* ws  = (float*)d_ws;

  unsigned* counts = (unsigned*)(ws + WS_COUNTS);
  float* avgp   = ws + WS_AVG;
  float* ent    = ws + WS_ENT;
  _Float16* wpk = (_Float16*)(ws + WS_WPK);
  float* avgred = ws + WS_AVGRED;

  k_conv_w<<<64, 640, 0, stream>>>(w, wpk, counts);
  k_fused<<<NBLK, THREADS, 0, stream>>>(x, wpk, b, cb, gum, out, counts, avgp);
  k_post<<<(T_ * G_) / 4 + GV / 4, 256, 0, stream>>>(counts, ent, avgp, avgred);
  k_final<<<1, GV, 0, stream>>>(avgred, ent, out + (size_t)N_ * G_ * D_);
}